// Round 1
// baseline (56878.687 us; speedup 1.0000x reference)
//
#include <hip/hip_runtime.h>
#include <hip/hip_bf16.h>

#define DMODEL 640
#define HDIM   1760
#define G4     7040      // 4*H
#define VOCAB  50257
#define VPAD   50304     // 393*128
#define SEQ    512
#define MROWS  4096      // B*S
#define NWG    220       // scan workgroups (220*8 = 1760 j's)

typedef __attribute__((ext_vector_type(8))) short short8_t;
typedef __attribute__((ext_vector_type(4))) short s16x4;
typedef __attribute__((ext_vector_type(4))) float f32x4;

static __device__ __forceinline__ float bf2f(short s) {
  union { unsigned int u; float f; } v;
  v.u = ((unsigned int)(unsigned short)s) << 16;
  return v.f;
}
static __device__ __forceinline__ short f2bf(float f) {
  union { float f; unsigned int u; } v; v.f = f;
  unsigned int r = v.u + 0x7fffu + ((v.u >> 16) & 1u);  // RNE, non-NaN inputs
  return (short)(r >> 16);
}

// ---------------- f32 -> bf16 conversion ----------------
__global__ void cvt_f32_bf16(const float* __restrict__ src, short* __restrict__ dst, long n) {
  long i = ((long)blockIdx.x * blockDim.x + threadIdx.x) * 8;
  if (i + 8 <= n) {
    float4 a = *(const float4*)(src + i);
    float4 b = *(const float4*)(src + i + 4);
    short8_t o;
    o[0] = f2bf(a.x); o[1] = f2bf(a.y); o[2] = f2bf(a.z); o[3] = f2bf(a.w);
    o[4] = f2bf(b.x); o[5] = f2bf(b.y); o[6] = f2bf(b.z); o[7] = f2bf(b.w);
    *(short8_t*)(dst + i) = o;
  } else {
    for (; i < n; ++i) dst[i] = f2bf(src[i]);
  }
}

// ---------------- embedding gather ----------------
__global__ void embed_gather(const int* __restrict__ ids, const float* __restrict__ emb,
                             short* __restrict__ x0) {
  int row = blockIdx.x;            // b*512+s
  int id  = ids[row];
  const float* s = emb + (long)id * DMODEL;
  short* d = x0 + (long)row * DMODEL;
  for (int c = threadIdx.x; c < DMODEL; c += blockDim.x) d[c] = f2bf(s[c]);
}

// ---------------- bf16 MFMA GEMM: C[M,N] = A[M,K] * B[N,K]^T ----------------
// A,B bf16 row-major; K % 32 == 0; M % 128 == 0; N edge handled by store guard
// (B buffer must be padded to ceil(N/128)*128 rows).
#define GLDS16(gp, lp) __builtin_amdgcn_global_load_lds( \
    (const __attribute__((address_space(1))) unsigned int*)(gp), \
    (__attribute__((address_space(3))) unsigned int*)(lp), 16, 0, 0)

template<int OUT_BF16>
__global__ __launch_bounds__(256, 2) void gemm_btn(
    const short* __restrict__ A, const short* __restrict__ B, void* __restrict__ C,
    int M, int N, int K)
{
  __shared__ short As[128 * 32];
  __shared__ short Bs[128 * 32];
  const int bn = blockIdx.x * 128, bm = blockIdx.y * 128;
  const int tid = threadIdx.x, lane = tid & 63, wid = tid >> 6;
  const int wm = (wid >> 1) * 64, wn = (wid & 1) * 64;

  f32x4 acc[4][4] = {};

  // staging: each wave stages chunks 2w, 2w+1 (1 KB each) of A and B tiles
  const int c0 = 2 * wid;
  const int srow = c0 * 16 + (lane >> 2);
  const int scol = (lane & 3) * 8;
  const long aoff0 = (long)(bm + srow) * K + scol;
  const long aoff1 = aoff0 + 16 * (long)K;
  const long boff0 = (long)(bn + srow) * K + scol;
  const long boff1 = boff0 + 16 * (long)K;
  short* Asw0 = As + c0 * 512; short* Asw1 = Asw0 + 512;
  short* Bsw0 = Bs + c0 * 512; short* Bsw1 = Bsw0 + 512;

  for (int bk = 0; bk < K; bk += 32) {
    GLDS16(A + aoff0 + bk, Asw0);
    GLDS16(A + aoff1 + bk, Asw1);
    GLDS16(B + boff0 + bk, Bsw0);
    GLDS16(B + boff1 + bk, Bsw1);
    __syncthreads();
    short8_t af[4], bfr[4];
#pragma unroll
    for (int m = 0; m < 4; ++m)
      af[m] = *(const short8_t*)&As[(wm + m * 16 + (lane & 15)) * 32 + (lane >> 4) * 8];
#pragma unroll
    for (int n = 0; n < 4; ++n)
      bfr[n] = *(const short8_t*)&Bs[(wn + n * 16 + (lane & 15)) * 32 + (lane >> 4) * 8];
#pragma unroll
    for (int m = 0; m < 4; ++m)
#pragma unroll
      for (int n = 0; n < 4; ++n)
        acc[m][n] = __builtin_amdgcn_mfma_f32_16x16x32_bf16(af[m], bfr[n], acc[m][n], 0, 0, 0);
    __syncthreads();
  }

#pragma unroll
  for (int m = 0; m < 4; ++m) {
#pragma unroll
    for (int n = 0; n < 4; ++n) {
      int col = bn + wn + n * 16 + (lane & 15);
      if (col < N) {
        int rbase = bm + wm + m * 16 + (lane >> 4) * 4;
#pragma unroll
        for (int i = 0; i < 4; ++i) {
          long idx = (long)(rbase + i) * N + col;
          if (OUT_BF16) ((short*)C)[idx] = f2bf(acc[m][n][i]);
          else          ((float*)C)[idx] = acc[m][n][i];
        }
      }
    }
  }
}

// ---------------- LSTM recurrent scan (persistent, 220 blocks) ----------------
// Each block owns 8 j-indices (j0..j0+7) across all 4 gates; W slice lives in LDS.
// Per step: g = h_{t-1} @ Wslice^T via MFMA (K split over 4 waves, LDS-reduced),
// then wave 0 applies gate nonlinearities, updates register c, writes bf16 h.
// Cross-block sync: device-scope atomic counter + threadfence release/acquire.
__global__ __launch_bounds__(256, 1) void lstm_scan(
    const short* __restrict__ whh,   // [7040][1760] bf16
    const short* __restrict__ xg,    // [4096][7040] bf16 = x @ w_ih^T
    const float* __restrict__ bih, const float* __restrict__ bhh,  // [7040]
    short* __restrict__ xout,        // [4096][1760] bf16 (h history = layer output)
    int* __restrict__ bar, int layer)
{
  __shared__ short Ws[32][1768];           // rows: [gate(4)][j(8)], padded cols
  __shared__ float red[4][2][64][4];       // K-split partial sums

  const int wg = blockIdx.x, tid = threadIdx.x, lane = tid & 63, wid = tid >> 6;
  const int j0 = wg * 8;

  // load W slice: slice row r -> global row (r>>3)*HDIM + j0 + (r&7)
  for (int c = tid; c < 32 * 440; c += 256) {    // 440 x s16x4 per row
    int r = c / 440, cc = (c % 440) * 4;
    int grow = (r >> 3) * HDIM + j0 + (r & 7);
    *(s16x4*)&Ws[r][cc] = *(const s16x4*)&whh[(long)grow * HDIM + cc];
  }

  const int b = lane & 15;
  const int jrel = (lane >> 4) * 4;        // valid for lane<32
  const bool active = (wid == 0) && (lane < 32) && (b < 8);

  float bI[4], bF[4], bG[4], bO[4];
  float cst[4] = {0.f, 0.f, 0.f, 0.f};
  if (active) {
#pragma unroll
    for (int i = 0; i < 4; ++i) {
      int j = j0 + jrel + i;
      bI[i] = bih[j]            + bhh[j];
      bF[i] = bih[HDIM + j]     + bhh[HDIM + j];
      bG[i] = bih[2 * HDIM + j] + bhh[2 * HDIM + j];
      bO[i] = bih[3 * HDIM + j] + bhh[3 * HDIM + j];
    }
  }

  const int ks0 = wid * 14, ks1 = (ks0 + 14 < 55) ? ks0 + 14 : 55;
  const int bc = (b < 7) ? b : 7;          // clamp pad batches (cols 8..15 discarded)
  const long hlane = (long)(bc * SEQ) * HDIM + (lane >> 4) * 8;
  const int awrow0 = lane & 15, awrow1 = 16 + (lane & 15);
  const int acol = (lane >> 4) * 8;

  __syncthreads();  // Ws ready

  for (int t = 0; t < SEQ; ++t) {
    // prefetch xg values for this step (independent of h)
    float xgv[4][4];
    if (active) {
      const short* xrow = xg + (long)(b * SEQ + t) * G4;
      s16x4 xi = *(const s16x4*)(xrow + j0 + jrel);
      s16x4 xf = *(const s16x4*)(xrow + HDIM + j0 + jrel);
      s16x4 xgg = *(const s16x4*)(xrow + 2 * HDIM + j0 + jrel);
      s16x4 xo = *(const s16x4*)(xrow + 3 * HDIM + j0 + jrel);
#pragma unroll
      for (int i = 0; i < 4; ++i) {
        xgv[0][i] = bf2f(xi[i]); xgv[1][i] = bf2f(xf[i]);
        xgv[2][i] = bf2f(xgg[i]); xgv[3][i] = bf2f(xo[i]);
      }
    }

    f32x4 acc0 = {0.f, 0.f, 0.f, 0.f}, acc1 = {0.f, 0.f, 0.f, 0.f};
    if (t > 0) {
      const short* hb = xout + hlane + (long)(t - 1) * HDIM;
      for (int kk = ks0; kk < ks1; ++kk) {
        short8_t bf = *(const short8_t*)(hb + kk * 32);
        short8_t a0 = *(const short8_t*)&Ws[awrow0][kk * 32 + acol];
        short8_t a1 = *(const short8_t*)&Ws[awrow1][kk * 32 + acol];
        acc0 = __builtin_amdgcn_mfma_f32_16x16x32_bf16(a0, bf, acc0, 0, 0, 0);
        acc1 = __builtin_amdgcn_mfma_f32_16x16x32_bf16(a1, bf, acc1, 0, 0, 0);
      }
    }
    *(f32x4*)&red[wid][0][lane][0] = acc0;
    *(f32x4*)&red[wid][1][lane][0] = acc1;
    __syncthreads();

    if (wid == 0) {
#pragma unroll
      for (int w = 1; w < 4; ++w) {
        acc0 += *(const f32x4*)&red[w][0][lane][0];
        acc1 += *(const f32x4*)&red[w][1][lane][0];
      }
      f32x4 fac, oac;   // bring f-gate / o-gate partials to lanes<32
#pragma unroll
      for (int i = 0; i < 4; ++i) {
        fac[i] = __shfl_xor(acc0[i], 32);
        oac[i] = __shfl_xor(acc1[i], 32);
      }
      if (active) {
        s16x4 hv;
#pragma unroll
        for (int i = 0; i < 4; ++i) {
          float pi = acc0[i] + xgv[0][i] + bI[i];
          float pf = fac[i]  + xgv[1][i] + bF[i];
          float pg = acc1[i] + xgv[2][i] + bG[i];
          float po = oac[i]  + xgv[3][i] + bO[i];
          float ig = 1.f / (1.f + __expf(-pi));
          float fg = 1.f / (1.f + __expf(-pf));
          float og = 1.f / (1.f + __expf(-po));
          float gg = tanhf(pg);
          cst[i] = fg * cst[i] + ig * gg;
          hv[i] = f2bf(og * tanhf(cst[i]));
        }
        *(s16x4*)(xout + (long)(b * SEQ + t) * HDIM + j0 + jrel) = hv;
      }
    }

    // inter-block step barrier (release/acquire)
    __threadfence();
    __syncthreads();
    if (tid == 0) {
      __hip_atomic_fetch_add(bar, 1, __ATOMIC_RELAXED, __HIP_MEMORY_SCOPE_AGENT);
      const int tgt = NWG * (layer * SEQ + t + 1);
      while (__hip_atomic_load(bar, __ATOMIC_RELAXED, __HIP_MEMORY_SCOPE_AGENT) < tgt) {}
    }
    __syncthreads();
    __threadfence();
  }
}

// ---------------- LayerNorm over H ----------------
__global__ __launch_bounds__(256) void ln_fwd(
    const short* __restrict__ x, const float* __restrict__ g, const float* __restrict__ bb,
    short* __restrict__ y)
{
  __shared__ float rs[8];
  const int row = blockIdx.x, tid = threadIdx.x;
  const short* xr = x + (long)row * HDIM;
  float s1 = 0.f, s2 = 0.f;
  for (int c = tid; c < HDIM; c += 256) { float f = bf2f(xr[c]); s1 += f; s2 += f * f; }
  for (int off = 32; off; off >>= 1) { s1 += __shfl_xor(s1, off); s2 += __shfl_xor(s2, off); }
  if ((tid & 63) == 0) { rs[(tid >> 6) * 2] = s1; rs[(tid >> 6) * 2 + 1] = s2; }
  __syncthreads();
  s1 = rs[0] + rs[2] + rs[4] + rs[6];
  s2 = rs[1] + rs[3] + rs[5] + rs[7];
  const float mu = s1 / HDIM;
  const float rstd = rsqrtf(s2 / HDIM - mu * mu + 1e-5f);
  for (int c = tid; c < HDIM; c += 256) {
    float f = bf2f(xr[c]);
    y[(long)row * HDIM + c] = f2bf((f - mu) * rstd * g[c] + bb[c]);
  }
}

// ---------------- host orchestration ----------------
extern "C" void kernel_launch(void* const* d_in, const int* in_sizes, int n_in,
                              void* d_out, int out_size, void* d_ws, size_t ws_size,
                              hipStream_t stream) {
  (void)in_sizes; (void)n_in; (void)out_size; (void)ws_size;
  const int*   ids  = (const int*)d_in[0];
  const float* emb  = (const float*)d_in[1];
  const float* wih[3] = {(const float*)d_in[2], (const float*)d_in[6], (const float*)d_in[10]};
  const float* whh[3] = {(const float*)d_in[3], (const float*)d_in[7], (const float*)d_in[11]};
  const float* bih[3] = {(const float*)d_in[4], (const float*)d_in[8], (const float*)d_in[12]};
  const float* bhh[3] = {(const float*)d_in[5], (const float*)d_in[9], (const float*)d_in[13]};
  const float* lng  = (const float*)d_in[14];
  const float* lnb  = (const float*)d_in[15];
  const float* prjw = (const float*)d_in[16];
  float* out = (float*)d_out;

  char* p = (char*)d_ws;
  auto alloc = [&](size_t bytes) { char* r = p; p += (bytes + 255) & ~(size_t)255; return r; };
  short* emb_b = (short*)alloc((size_t)VPAD * DMODEL * 2);   // 64.4 MB (pad rows garbage-ok)
  short* wbuf  = (short*)alloc((size_t)G4 * HDIM * 2);       // 24.8 MB (wih/whh/proj reuse)
  short* xgbuf = (short*)alloc((size_t)MROWS * G4 * 2);      // 57.7 MB
  short* x0    = (short*)alloc((size_t)MROWS * DMODEL * 2);
  short* xb1   = (short*)alloc((size_t)MROWS * HDIM * 2);
  short* xb2   = (short*)alloc((size_t)MROWS * HDIM * 2);
  short* pbuf  = (short*)alloc((size_t)MROWS * DMODEL * 2);
  int*   bar   = (int*)alloc(256);

  hipMemsetAsync(bar, 0, 4, stream);

  auto cvt = [&](const float* s, short* d, long n) {
    int blocks = (int)((n / 8 + 255) / 256);
    cvt_f32_bf16<<<dim3(blocks), dim3(256), 0, stream>>>(s, d, n);
  };

  cvt(emb, emb_b, (long)VOCAB * DMODEL);
  embed_gather<<<dim3(MROWS), dim3(256), 0, stream>>>(ids, emb, x0);

  short* xin = x0; int kin = DMODEL;
  short* xouts[3] = {xb1, xb2, xb1};
  for (int l = 0; l < 3; ++l) {
    cvt(wih[l], wbuf, (long)G4 * kin);
    gemm_btn<1><<<dim3(G4 / 128, MROWS / 128), dim3(256), 0, stream>>>(
        xin, wbuf, (void*)xgbuf, MROWS, G4, kin);
    cvt(whh[l], wbuf, (long)G4 * HDIM);
    lstm_scan<<<dim3(NWG), dim3(256), 0, stream>>>(
        wbuf, xgbuf, bih[l], bhh[l], xouts[l], bar, l);
    xin = xouts[l]; kin = HDIM;
  }

  ln_fwd<<<dim3(MROWS), dim3(256), 0, stream>>>(xb1, lng, lnb, xb2);
  cvt(prjw, wbuf, (long)DMODEL * HDIM);
  gemm_btn<1><<<dim3(DMODEL / 128, MROWS / 128), dim3(256), 0, stream>>>(
      xb2, wbuf, (void*)pbuf, MROWS, DMODEL, HDIM);
  gemm_btn<0><<<dim3((VOCAB + 127) / 128, MROWS / 128), dim3(256), 0, stream>>>(
      pbuf, emb_b, (void*)out, MROWS, VOCAB, DMODEL);
}

// Round 2
// 8669.846 us; speedup vs baseline: 6.5605x; 6.5605x over previous
//
#include <hip/hip_runtime.h>
#include <hip/hip_bf16.h>

#define DMODEL 640
#define HDIM   1760
#define G4     7040      // 4*H
#define VOCAB  50257
#define VPAD   50304     // 393*128
#define SEQ    512
#define MROWS  4096      // B*S
#define NWG    220       // scan workgroups (220*8 = 1760 j's)
#define NCNT   8         // spread arrival counters (one cache line each)
#define WSTRIDE 1800     // Ws row stride in shorts (3600B -> 2-way bank alias = free)

typedef __attribute__((ext_vector_type(8))) short short8_t;
typedef __attribute__((ext_vector_type(4))) short s16x4;
typedef __attribute__((ext_vector_type(4))) float f32x4;

static __device__ __forceinline__ float bf2f(short s) {
  union { unsigned int u; float f; } v;
  v.u = ((unsigned int)(unsigned short)s) << 16;
  return v.f;
}
static __device__ __forceinline__ short f2bf(float f) {
  union { float f; unsigned int u; } v; v.f = f;
  unsigned int r = v.u + 0x7fffu + ((v.u >> 16) & 1u);  // RNE, non-NaN inputs
  return (short)(r >> 16);
}

// coherent (LLC-direct, bypass L1/L2) 16B load / 8B store for cross-XCD h exchange
static __device__ __forceinline__ short8_t ld16_coh(const short* p) {
  short8_t r;
  asm volatile("global_load_dwordx4 %0, %1, off sc0 sc1" : "=v"(r) : "v"(p));
  return r;
}
static __device__ __forceinline__ void st8_coh(short* p, s16x4 v) {
  asm volatile("global_store_dwordx2 %0, %1, off sc0 sc1" :: "v"(p), "v"(v) : "memory");
}

// ---------------- f32 -> bf16 conversion ----------------
__global__ void cvt_f32_bf16(const float* __restrict__ src, short* __restrict__ dst, long n) {
  long i = ((long)blockIdx.x * blockDim.x + threadIdx.x) * 8;
  if (i + 8 <= n) {
    float4 a = *(const float4*)(src + i);
    float4 b = *(const float4*)(src + i + 4);
    short8_t o;
    o[0] = f2bf(a.x); o[1] = f2bf(a.y); o[2] = f2bf(a.z); o[3] = f2bf(a.w);
    o[4] = f2bf(b.x); o[5] = f2bf(b.y); o[6] = f2bf(b.z); o[7] = f2bf(b.w);
    *(short8_t*)(dst + i) = o;
  } else {
    for (; i < n; ++i) dst[i] = f2bf(src[i]);
  }
}

// ---------------- embedding gather ----------------
__global__ void embed_gather(const int* __restrict__ ids, const float* __restrict__ emb,
                             short* __restrict__ x0) {
  int row = blockIdx.x;            // b*512+s
  int id  = ids[row];
  const float* s = emb + (long)id * DMODEL;
  short* d = x0 + (long)row * DMODEL;
  for (int c = threadIdx.x; c < DMODEL; c += blockDim.x) d[c] = f2bf(s[c]);
}

// ---------------- bf16 MFMA GEMM: C[M,N] = A[M,K] * B[N,K]^T ----------------
#define GLDS16(gp, lp) __builtin_amdgcn_global_load_lds( \
    (const __attribute__((address_space(1))) unsigned int*)(gp), \
    (__attribute__((address_space(3))) unsigned int*)(lp), 16, 0, 0)

template<int OUT_BF16>
__global__ __launch_bounds__(256, 2) void gemm_btn(
    const short* __restrict__ A, const short* __restrict__ B, void* __restrict__ C,
    int M, int N, int K)
{
  __shared__ short As[128 * 32];
  __shared__ short Bs[128 * 32];
  const int bn = blockIdx.x * 128, bm = blockIdx.y * 128;
  const int tid = threadIdx.x, lane = tid & 63, wid = tid >> 6;
  const int wm = (wid >> 1) * 64, wn = (wid & 1) * 64;

  f32x4 acc[4][4] = {};

  const int c0 = 2 * wid;
  const int srow = c0 * 16 + (lane >> 2);
  const int scol = (lane & 3) * 8;
  const long aoff0 = (long)(bm + srow) * K + scol;
  const long aoff1 = aoff0 + 16 * (long)K;
  const long boff0 = (long)(bn + srow) * K + scol;
  const long boff1 = boff0 + 16 * (long)K;
  short* Asw0 = As + c0 * 512; short* Asw1 = Asw0 + 512;
  short* Bsw0 = Bs + c0 * 512; short* Bsw1 = Bsw0 + 512;

  for (int bk = 0; bk < K; bk += 32) {
    GLDS16(A + aoff0 + bk, Asw0);
    GLDS16(A + aoff1 + bk, Asw1);
    GLDS16(B + boff0 + bk, Bsw0);
    GLDS16(B + boff1 + bk, Bsw1);
    __syncthreads();
    short8_t af[4], bfr[4];
#pragma unroll
    for (int m = 0; m < 4; ++m)
      af[m] = *(const short8_t*)&As[(wm + m * 16 + (lane & 15)) * 32 + (lane >> 4) * 8];
#pragma unroll
    for (int n = 0; n < 4; ++n)
      bfr[n] = *(const short8_t*)&Bs[(wn + n * 16 + (lane & 15)) * 32 + (lane >> 4) * 8];
#pragma unroll
    for (int m = 0; m < 4; ++m)
#pragma unroll
      for (int n = 0; n < 4; ++n)
        acc[m][n] = __builtin_amdgcn_mfma_f32_16x16x32_bf16(af[m], bfr[n], acc[m][n], 0, 0, 0);
    __syncthreads();
  }

#pragma unroll
  for (int m = 0; m < 4; ++m) {
#pragma unroll
    for (int n = 0; n < 4; ++n) {
      int col = bn + wn + n * 16 + (lane & 15);
      if (col < N) {
        int rbase = bm + wm + m * 16 + (lane >> 4) * 4;
#pragma unroll
        for (int i = 0; i < 4; ++i) {
          long idx = (long)(rbase + i) * N + col;
          if (OUT_BF16) ((short*)C)[idx] = f2bf(acc[m][n][i]);
          else          ((float*)C)[idx] = acc[m][n][i];
        }
      }
    }
  }
}

// ---------------- LSTM recurrent scan (persistent, 220 blocks) ----------------
// h exchange goes through the coherent LLC via sc0/sc1 flagged ops -> no
// __threadfence. Step barrier: 8 spread arrival counters (relaxed RMW),
// wg0 aggregates and publishes monotonic `go`; others spin on a plain load.
__global__ __launch_bounds__(256, 1) void lstm_scan(
    const short* __restrict__ whh,   // [7040][1760] bf16
    const short* __restrict__ xg,    // [4096][7040] bf16 = x @ w_ih^T
    const float* __restrict__ bih, const float* __restrict__ bhh,  // [7040]
    short* __restrict__ xout,        // [4096][1760] bf16 (h history = layer output)
    int* __restrict__ sync, int layer)
{
  __shared__ short Ws[32][WSTRIDE];        // rows: [gate(4)][j(8)], cols 0..1759 data, 1760..1791 zero
  __shared__ float red[4][2][64][4];       // K-split partial sums

  const int wg = blockIdx.x, tid = threadIdx.x, lane = tid & 63, wid = tid >> 6;
  const int j0 = wg * 8;

  // load W slice: slice row r -> global row (r>>3)*HDIM + j0 + (r&7); zero-pad cols
  for (int c = tid; c < 32 * 448; c += 256) {    // 448 x s16x4 per row (1792 cols)
    int r = c / 448, cc = (c % 448) * 4;
    s16x4 v = {0, 0, 0, 0};
    if (cc < HDIM) {
      int grow = (r >> 3) * HDIM + j0 + (r & 7);
      v = *(const s16x4*)&whh[(long)grow * HDIM + cc];
    }
    *(s16x4*)&Ws[r][cc] = v;
  }

  const int b = lane & 15;
  const int jrel = (lane >> 4) * 4;        // valid for lane<32
  const bool active = (wid == 0) && (lane < 32) && (b < 8);

  float bI[4], bF[4], bG[4], bO[4];
  float cst[4] = {0.f, 0.f, 0.f, 0.f};
  if (active) {
#pragma unroll
    for (int i = 0; i < 4; ++i) {
      int j = j0 + jrel + i;
      bI[i] = bih[j]            + bhh[j];
      bF[i] = bih[HDIM + j]     + bhh[HDIM + j];
      bG[i] = bih[2 * HDIM + j] + bhh[2 * HDIM + j];
      bO[i] = bih[3 * HDIM + j] + bhh[3 * HDIM + j];
    }
  }

  const int ks0 = wid * 14;                // 56 chunks of 32, uniform 14/wave
  const int bc = (b < 7) ? b : 7;          // clamp pad batches (cols 8..15 discarded)
  const long hlane = (long)(bc * SEQ) * HDIM + (lane >> 4) * 8;
  const int awrow0 = lane & 15, awrow1 = 16 + (lane & 15);
  const int acol = (lane >> 4) * 8;

  int* cnts = sync;                        // 8 counters, 128B apart
  int* gof  = sync + 256;                  // go flag at +1024B

  __syncthreads();  // Ws ready

  for (int t = 0; t < SEQ; ++t) {
    // xg for this step (plain cached loads; needed only after MFMA+reduce)
    s16x4 xi, xf, xgg, xo;
    if (active) {
      const short* xrow = xg + (long)(b * SEQ + t) * G4;
      xi  = *(const s16x4*)(xrow + j0 + jrel);
      xf  = *(const s16x4*)(xrow + HDIM + j0 + jrel);
      xgg = *(const s16x4*)(xrow + 2 * HDIM + j0 + jrel);
      xo  = *(const s16x4*)(xrow + 3 * HDIM + j0 + jrel);
    }

    f32x4 acc0 = {0.f, 0.f, 0.f, 0.f}, acc1 = {0.f, 0.f, 0.f, 0.f};
    if (t > 0) {
      const short* hb = xout + hlane + (long)(t - 1) * HDIM;
      short8_t hreg[14];
#pragma unroll
      for (int kkl = 0; kkl < 14; ++kkl)
        hreg[kkl] = ld16_coh(hb + (ks0 + kkl) * 32);
      asm volatile("s_waitcnt vmcnt(0)" ::: "memory");
      __builtin_amdgcn_sched_barrier(0);
#pragma unroll
      for (int kkl = 0; kkl < 14; ++kkl) {
        int kc = (ks0 + kkl) * 32 + acol;
        short8_t a0 = *(const short8_t*)&Ws[awrow0][kc];
        short8_t a1 = *(const short8_t*)&Ws[awrow1][kc];
        acc0 = __builtin_amdgcn_mfma_f32_16x16x32_bf16(a0, hreg[kkl], acc0, 0, 0, 0);
        acc1 = __builtin_amdgcn_mfma_f32_16x16x32_bf16(a1, hreg[kkl], acc1, 0, 0, 0);
      }
    }
    *(f32x4*)&red[wid][0][lane][0] = acc0;
    *(f32x4*)&red[wid][1][lane][0] = acc1;
    __syncthreads();

    if (wid == 0) {
#pragma unroll
      for (int w = 1; w < 4; ++w) {
        acc0 += *(const f32x4*)&red[w][0][lane][0];
        acc1 += *(const f32x4*)&red[w][1][lane][0];
      }
      f32x4 fac, oac;   // bring f-gate / o-gate partials to lanes<32
#pragma unroll
      for (int i = 0; i < 4; ++i) {
        fac[i] = __shfl_xor(acc0[i], 32);
        oac[i] = __shfl_xor(acc1[i], 32);
      }
      if (active) {
        s16x4 hv;
#pragma unroll
        for (int i = 0; i < 4; ++i) {
          float pi = acc0[i] + bf2f(xi[i])  + bI[i];
          float pf = fac[i]  + bf2f(xf[i])  + bF[i];
          float pg = acc1[i] + bf2f(xgg[i]) + bG[i];
          float po = oac[i]  + bf2f(xo[i])  + bO[i];
          float ig = 1.f / (1.f + __expf(-pi));
          float fg = 1.f / (1.f + __expf(-pf));
          float og = 1.f / (1.f + __expf(-po));
          float gg = tanhf(pg);
          cst[i] = fg * cst[i] + ig * gg;
          hv[i] = f2bf(og * tanhf(cst[i]));
        }
        st8_coh(xout + (long)(b * SEQ + t) * HDIM + j0 + jrel, hv);
      }
      asm volatile("s_waitcnt vmcnt(0)" ::: "memory");   // h at LLC before arrival
    }
    __syncthreads();

    if (tid == 0) {
      const int gstep = layer * SEQ + t + 1;
      __hip_atomic_fetch_add(&cnts[(wg & (NCNT - 1)) * 32], 1,
                             __ATOMIC_RELAXED, __HIP_MEMORY_SCOPE_AGENT);
      if (t < SEQ - 1) {
        if (wg == 0) {
          const int target = NWG * gstep;
          int s;
          do {
            s = 0;
#pragma unroll
            for (int c = 0; c < NCNT; ++c)
              s += __hip_atomic_load(&cnts[c * 32], __ATOMIC_RELAXED, __HIP_MEMORY_SCOPE_AGENT);
          } while (s < target);
          __hip_atomic_store(gof, gstep, __ATOMIC_RELAXED, __HIP_MEMORY_SCOPE_AGENT);
        } else {
          while (__hip_atomic_load(gof, __ATOMIC_RELAXED, __HIP_MEMORY_SCOPE_AGENT) < gstep)
            __builtin_amdgcn_s_sleep(1);
        }
      }
    }
    __syncthreads();
  }
}

// ---------------- LayerNorm over H ----------------
__global__ __launch_bounds__(256) void ln_fwd(
    const short* __restrict__ x, const float* __restrict__ g, const float* __restrict__ bb,
    short* __restrict__ y)
{
  __shared__ float rs[8];
  const int row = blockIdx.x, tid = threadIdx.x;
  const short* xr = x + (long)row * HDIM;
  float s1 = 0.f, s2 = 0.f;
  for (int c = tid; c < HDIM; c += 256) { float f = bf2f(xr[c]); s1 += f; s2 += f * f; }
  for (int off = 32; off; off >>= 1) { s1 += __shfl_xor(s1, off); s2 += __shfl_xor(s2, off); }
  if ((tid & 63) == 0) { rs[(tid >> 6) * 2] = s1; rs[(tid >> 6) * 2 + 1] = s2; }
  __syncthreads();
  s1 = rs[0] + rs[2] + rs[4] + rs[6];
  s2 = rs[1] + rs[3] + rs[5] + rs[7];
  const float mu = s1 / HDIM;
  const float rstd = rsqrtf(s2 / HDIM - mu * mu + 1e-5f);
  for (int c = tid; c < HDIM; c += 256) {
    float f = bf2f(xr[c]);
    y[(long)row * HDIM + c] = f2bf((f - mu) * rstd * g[c] + bb[c]);
  }
}

// ---------------- host orchestration ----------------
extern "C" void kernel_launch(void* const* d_in, const int* in_sizes, int n_in,
                              void* d_out, int out_size, void* d_ws, size_t ws_size,
                              hipStream_t stream) {
  (void)in_sizes; (void)n_in; (void)out_size; (void)ws_size;
  const int*   ids  = (const int*)d_in[0];
  const float* emb  = (const float*)d_in[1];
  const float* wih[3] = {(const float*)d_in[2], (const float*)d_in[6], (const float*)d_in[10]};
  const float* whh[3] = {(const float*)d_in[3], (const float*)d_in[7], (const float*)d_in[11]};
  const float* bih[3] = {(const float*)d_in[4], (const float*)d_in[8], (const float*)d_in[12]};
  const float* bhh[3] = {(const float*)d_in[5], (const float*)d_in[9], (const float*)d_in[13]};
  const float* lng  = (const float*)d_in[14];
  const float* lnb  = (const float*)d_in[15];
  const float* prjw = (const float*)d_in[16];
  float* out = (float*)d_out;

  char* p = (char*)d_ws;
  auto alloc = [&](size_t bytes) { char* r = p; p += (bytes + 255) & ~(size_t)255; return r; };
  short* emb_b = (short*)alloc((size_t)VPAD * DMODEL * 2);   // 64.4 MB
  short* wbuf  = (short*)alloc((size_t)G4 * HDIM * 2);       // 24.8 MB
  short* xgbuf = (short*)alloc((size_t)MROWS * G4 * 2);      // 57.7 MB
  short* x0    = (short*)alloc((size_t)MROWS * DMODEL * 2);
  short* xb1   = (short*)alloc((size_t)MROWS * HDIM * 2);
  short* xb2   = (short*)alloc((size_t)MROWS * HDIM * 2);
  short* pbuf  = (short*)alloc((size_t)MROWS * DMODEL * 2);
  int*   sync  = (int*)alloc(4096);

  hipMemsetAsync(sync, 0, 4096, stream);

  auto cvt = [&](const float* s, short* d, long n) {
    int blocks = (int)((n / 8 + 255) / 256);
    cvt_f32_bf16<<<dim3(blocks), dim3(256), 0, stream>>>(s, d, n);
  };

  cvt(emb, emb_b, (long)VOCAB * DMODEL);
  embed_gather<<<dim3(MROWS), dim3(256), 0, stream>>>(ids, emb, x0);

  short* xin = x0; int kin = DMODEL;
  short* xouts[3] = {xb1, xb2, xb1};
  for (int l = 0; l < 3; ++l) {
    cvt(wih[l], wbuf, (long)G4 * kin);
    gemm_btn<1><<<dim3(G4 / 128, MROWS / 128), dim3(256), 0, stream>>>(
        xin, wbuf, (void*)xgbuf, MROWS, G4, kin);
    cvt(whh[l], wbuf, (long)G4 * HDIM);
    lstm_scan<<<dim3(NWG), dim3(256), 0, stream>>>(
        wbuf, xgbuf, bih[l], bhh[l], xouts[l], sync, l);
    xin = xouts[l]; kin = HDIM;
  }

  ln_fwd<<<dim3(MROWS), dim3(256), 0, stream>>>(xb1, lng, lnb, xb2);
  cvt(prjw, wbuf, (long)DMODEL * HDIM);
  gemm_btn<1><<<dim3(DMODEL / 128, MROWS / 128), dim3(256), 0, stream>>>(
      xb2, wbuf, (void*)pbuf, MROWS, DMODEL, HDIM);
  gemm_btn<0><<<dim3((VOCAB + 127) / 128, MROWS / 128), dim3(256), 0, stream>>>(
      pbuf, emb_b, (void*)out, MROWS, VOCAB, DMODEL);
}